// Round 8
// baseline (414.112 us; speedup 1.0000x reference)
//
#include <hip/hip_runtime.h>
#include <hip/hip_bf16.h>

typedef unsigned short u16;
typedef __attribute__((ext_vector_type(8))) short bf16x8;
typedef __attribute__((ext_vector_type(4))) float f32x4;

__device__ __forceinline__ float bf2f(u16 u){
  union { unsigned int i; float f; } v; v.i = ((unsigned int)u) << 16; return v.f;
}
__device__ __forceinline__ u16 f2bf(float f){
  union { float f; unsigned int i; } v; v.f = f;
  unsigned int i = v.i;
  return (u16)((i + 0x7fffu + ((i >> 16) & 1u)) >> 16);
}
// packed bf16 convert (v_cvt_pk_bf16_f32 on gfx950)
__device__ __forceinline__ unsigned int pk2(float a, float b){
  union { __hip_bfloat162 v; unsigned int u; } c;
  c.v = __float22bfloat162_rn(float2{a, b});
  return c.u;
}
__device__ __forceinline__ float ldin(const void* p, int i, int f){
  return f ? ((const float*)p)[i] : bf2f(((const u16*)p)[i]);
}

// ---------------------------------------------------------------------------
// Kernel P: MERGED prep — sniff + weight transpose + msa LN + pair LN/z.
// (unchanged from R7 — rest went 177 -> 139 with this merge)
// ---------------------------------------------------------------------------
__global__ __launch_bounds__(256) void k_prep(
    const void* __restrict__ msa,  const void* __restrict__ pair,
    const void* __restrict__ qng,  const void* __restrict__ qnb,
    const void* __restrict__ png,  const void* __restrict__ pnb,
    const void* __restrict__ w2d,
    const void* __restrict__ wq, const void* __restrict__ wk,
    const void* __restrict__ wv, const void* __restrict__ wg,
    const void* __restrict__ wo,
    u16* __restrict__ Wt, u16* __restrict__ wot,
    u16* __restrict__ m_bf, u16* __restrict__ z_bf,
    int* __restrict__ flagp)
{
  __shared__ u16 shm[11008];          // 22 KB scratch (max of branch uses)
  __shared__ int flag_sh;
  const int t = threadIdx.x;
  const int bid = blockIdx.x;

  // ---- local dtype sniff (wave 0) ----
  if (t < 64) {
    const unsigned int* msa_w = (const unsigned int*)msa;
    int lo0 = 0, expok = 0;
    #pragma unroll
    for (int j = 0; j < 4; ++j) {
      unsigned int w = msa_w[t * 4 + j];
      if ((w & 0xffffu) == 0u) lo0++;
      unsigned int e = (w >> 7) & 0xffu;
      if (e >= 110u && e <= 140u) expok++;
    }
    #pragma unroll
    for (int off = 1; off < 64; off <<= 1) {
      lo0   += __shfl_xor(lo0,   off, 64);
      expok += __shfl_xor(expok, off, 64);
    }
    if (t == 0) flag_sh = (lo0 > 200) ? 1 : ((expok > 200) ? 0 : 1);
  }
  __syncthreads();
  const int flag = flag_sh;
  if (bid == 0 && t == 0) *flagp = flag;

  if (bid < 80) {
    // ---- weight transpose ----
    u16* T = shm;                      // [64][72]
    const int mat = bid >> 4, tile = bid & 15;
    const int R0 = (tile >> 2) * 64, C0 = (tile & 3) * 64;
    const void* src = (mat == 0) ? wq : (mat == 1) ? wk : (mat == 2) ? wv
                    : (mat == 3) ? wg : wo;
    u16* dst = (mat < 4) ? (Wt + mat * 65536) : wot;
    {
      int i = t >> 2, j0 = (t & 3) * 16;
      #pragma unroll
      for (int e = 0; e < 8; ++e) {
        float a = ldin(src, (R0 + i) * 256 + C0 + j0 + 2*e,     flag);
        float b = ldin(src, (R0 + i) * 256 + C0 + j0 + 2*e + 1, flag);
        *(unsigned int*)(T + i * 72 + j0 + 2*e) = pk2(a, b);
      }
    }
    __syncthreads();
    {
      int j = t >> 2, i0 = (t & 3) * 16;
      u16 o[16];
      #pragma unroll
      for (int e = 0; e < 16; ++e) o[e] = T[(i0 + e) * 72 + j];
      *(uint4*)(dst + (C0 + j) * 256 + R0 + i0)     = *(const uint4*)o;
      *(uint4*)(dst + (C0 + j) * 256 + R0 + i0 + 8) = *(const uint4*)(o + 8);
    }
  } else if (bid < 8272) {
    // ---- msa LayerNorm (4 rows/block) ----
    int wave = t >> 6, lane = t & 63;
    int row = (bid - 80) * 4 + wave;            // 0..32767
    float x[4];
    if (flag) {
      float4 f4 = *((const float4*)msa + row * 64 + lane);
      x[0]=f4.x; x[1]=f4.y; x[2]=f4.z; x[3]=f4.w;
    } else {
      uint2 u = *((const uint2*)msa + row * 64 + lane);
      const u16* h = (const u16*)&u;
      #pragma unroll
      for (int j = 0; j < 4; ++j) x[j] = bf2f(h[j]);
    }
    float s = 0.f, sq = 0.f;
    #pragma unroll
    for (int j = 0; j < 4; ++j) { s += x[j]; sq += x[j] * x[j]; }
    #pragma unroll
    for (int off = 1; off < 64; off <<= 1) {
      s  += __shfl_xor(s,  off, 64);
      sq += __shfl_xor(sq, off, 64);
    }
    float mu = s * (1.f / 256.f);
    float var = sq * (1.f / 256.f) - mu * mu;
    float rs = rsqrtf(var + 1e-5f);
    float y[4];
    #pragma unroll
    for (int j = 0; j < 4; ++j) {
      int c = lane * 4 + j;
      y[j] = (x[j] - mu) * rs * ldin(qng, c, flag) + ldin(qnb, c, flag);
    }
    uint2 o2;
    o2.x = pk2(y[0], y[1]);
    o2.y = pk2(y[2], y[3]);
    *((uint2*)m_bf + row * 64 + lane) = o2;
  } else {
    // ---- pair LayerNorm + z via MFMA ----
    u16* As = shm;                     // [64][136]
    u16* Bs = shm + 64 * 136;          // [16][136]
    const int lane = t & 63, wave = t >> 6;
    const int g = lane >> 4, l15 = lane & 15;
    const int rowBase = (bid - 8272) * 64;      // of 65536 (q*256+k)

    if (t < 128) {
      #pragma unroll
      for (int n = 0; n < 16; ++n)
        Bs[n * 136 + t] = (n < 8) ? f2bf(ldin(w2d, t * 8 + n, flag)) : (u16)0;
    }
    {
      int lrow = t >> 2, cb = (t & 3) * 32;
      int base = (rowBase + lrow) * 128 + cb;
      float x[32];
      if (flag) {
        const float* p = (const float*)pair + base;
        #pragma unroll
        for (int j = 0; j < 8; ++j) {
          float4 f4 = *(const float4*)(p + 4 * j);
          x[4*j] = f4.x; x[4*j+1] = f4.y; x[4*j+2] = f4.z; x[4*j+3] = f4.w;
        }
      } else {
        const u16* p = (const u16*)pair + base;
        #pragma unroll
        for (int j = 0; j < 4; ++j) {
          uint4 u = *(const uint4*)(p + 8 * j);
          const u16* h = (const u16*)&u;
          #pragma unroll
          for (int e = 0; e < 8; ++e) x[8*j+e] = bf2f(h[e]);
        }
      }
      float s = 0.f, sq = 0.f;
      #pragma unroll
      for (int j = 0; j < 32; ++j) { s += x[j]; sq += x[j] * x[j]; }
      s  += __shfl_xor(s, 1, 64);  s  += __shfl_xor(s, 2, 64);
      sq += __shfl_xor(sq, 1, 64); sq += __shfl_xor(sq, 2, 64);
      float mu = s * (1.f / 128.f);
      float var = sq * (1.f / 128.f) - mu * mu;
      float rs = rsqrtf(var + 1e-5f);
      float n_[32];
      #pragma unroll
      for (int j = 0; j < 32; ++j) {
        int c = cb + j;
        n_[j] = (x[j] - mu) * rs * ldin(png, c, flag) + ldin(pnb, c, flag);
      }
      u16* dst = As + lrow * 136 + cb;
      #pragma unroll
      for (int j = 0; j < 16; ++j)
        *(unsigned int*)(dst + 2*j) = pk2(n_[2*j], n_[2*j+1]);
    }
    __syncthreads();

    f32x4 accz = {0.f, 0.f, 0.f, 0.f};
    #pragma unroll
    for (int kb = 0; kb < 4; ++kb) {
      bf16x8 a = *(const bf16x8*)(As + (wave * 16 + l15) * 136 + kb * 32 + g * 8);
      bf16x8 b = *(const bf16x8*)(Bs + l15 * 136 + kb * 32 + g * 8);
      accz = __builtin_amdgcn_mfma_f32_16x16x32_bf16(a, b, accz, 0, 0, 0);
    }
    if (l15 < 8) {
      #pragma unroll
      for (int r = 0; r < 4; ++r)
        z_bf[l15 * 65536 + rowBase + wave * 16 + g * 4 + r] = f2bf(accz[r]);
    }
  }
}

// ---------------------------------------------------------------------------
// Kernel Q: QKVG projection GEMM.  Round-16: SPLIT from the fused kernel —
// pure GEMM M=32768, N=1024 (mat[4] x h[8] x d[32]), K=256, zero LDS,
// k_outproj's proven 64x128-tile structure at (256,4) -> 4 blocks/CU.
// grid (512 row-tiles, 8): y -> (matid = y>>1, colhalf = y&1).
// mat 0 (Q): x scale, row-major [row][h*32+d].   mat 1 (K): row-major.
// mat 2 (V): swapped-operand mfma (verified R5) -> transposed store
//            Vt[s][h][d][k], contiguous in l15 (32-B segments).
// mat 3 (G): sigmoid(acc + bg) applied here, row-major.
// ---------------------------------------------------------------------------
__global__ __launch_bounds__(256, 4) void k_qkvg(
    const u16* __restrict__ m_bf, const u16* __restrict__ Wt,
    const void* __restrict__ bg, const int* __restrict__ flagp,
    u16* __restrict__ Qw, u16* __restrict__ Kw,
    u16* __restrict__ Vt, u16* __restrict__ Gw)
{
  const int flag = *flagp;
  const int t = threadIdx.x, lane = t & 63, wave = t >> 6;
  const int wm = (wave >> 1) * 32, wn = (wave & 1) * 64;
  const int rowBase = blockIdx.x * 64;
  const int matid = blockIdx.y >> 1, half = blockIdx.y & 1;
  const int g = lane >> 4, l15 = lane & 15;
  const float scale = 0.17677669529663687f;  // 1/sqrt(32)

  bf16x8 af[8][2];
  #pragma unroll
  for (int kb = 0; kb < 8; ++kb)
    #pragma unroll
    for (int mt = 0; mt < 2; ++mt)
      af[kb][mt] = *(const bf16x8*)(
          m_bf + (rowBase + wm + mt * 16 + l15) * 256 + kb * 32 + g * 8);

  const u16* W = Wt + matid * 65536 + (half * 128 + wn) * 256;
  f32x4 acc[2][4];
  f32x4 zero = {0.f, 0.f, 0.f, 0.f};
  #pragma unroll
  for (int i = 0; i < 2; ++i)
    #pragma unroll
    for (int j = 0; j < 4; ++j) acc[i][j] = zero;
  #pragma unroll
  for (int kb = 0; kb < 8; ++kb) {
    bf16x8 bb[4];
    #pragma unroll
    for (int nt = 0; nt < 4; ++nt)
      bb[nt] = *(const bf16x8*)(W + (nt * 16 + l15) * 256 + kb * 32 + g * 8);
    #pragma unroll
    for (int mt = 0; mt < 2; ++mt)
      #pragma unroll
      for (int nt = 0; nt < 4; ++nt) {
        if (matid == 2)   // swapped: out col l15 = m-row, out row = d
          acc[mt][nt] = __builtin_amdgcn_mfma_f32_16x16x32_bf16(
              bb[nt], af[kb][mt], acc[mt][nt], 0, 0, 0);
        else              // normal: out row = m-row, out col l15 = d
          acc[mt][nt] = __builtin_amdgcn_mfma_f32_16x16x32_bf16(
              af[kb][mt], bb[nt], acc[mt][nt], 0, 0, 0);
      }
  }
  if (matid == 2) {
    #pragma unroll
    for (int mt = 0; mt < 2; ++mt) {
      const int rg = rowBase + wm + mt * 16;
      const int s = rg >> 8, k0 = rg & 255;
      #pragma unroll
      for (int nt = 0; nt < 4; ++nt)
        #pragma unroll
        for (int r = 0; r < 4; ++r) {
          int dcol = half * 128 + wn + nt * 16 + g * 4 + r;   // h*32+d
          Vt[((s * 8 + (dcol >> 5)) * 32 + (dcol & 31)) * 256 + k0 + l15] =
              f2bf(acc[mt][nt][r]);
        }
    }
  } else {
    u16* dst = (matid == 0) ? Qw : (matid == 1) ? Kw : Gw;
    #pragma unroll
    for (int mt = 0; mt < 2; ++mt)
      #pragma unroll
      for (int nt = 0; nt < 4; ++nt)
        #pragma unroll
        for (int r = 0; r < 4; ++r) {
          int row = rowBase + wm + mt * 16 + g * 4 + r;
          int col = half * 128 + wn + nt * 16 + l15;
          float v = acc[mt][nt][r];
          if (matid == 0) v *= scale;
          else if (matid == 3)
            v = 1.0f / (1.0f + __expf(-(v + ldin(bg, col, flag))));
          dst[row * 256 + col] = f2bf(v);
        }
  }
}

// ---------------------------------------------------------------------------
// Kernel A: attention only.  Round-16: NO LDS staging (K/V/Q/z slices are
// 16-128 KB and L2/L3-hot; staging data that cache-fits is pure overhead).
// Streamed kc-loop (online sum — no S[16] array) -> ~90 VGPR ->
// (256,4) = 4 blocks/CU, grid 1024 = exactly 4/CU: the serial chain that
// was latency-bound at 2 blocks/CU now has 4 waves/SIMD to hide under.
// All fragment/index math verbatim from the verified R5 kernel.
// ---------------------------------------------------------------------------
__global__ __launch_bounds__(256, 4) void k_attn(
    const u16* __restrict__ Qw, const u16* __restrict__ Kw,
    const u16* __restrict__ Vt, const u16* __restrict__ Gw,
    const u16* __restrict__ z_bf, const void* __restrict__ mask,
    const int* __restrict__ flagp, u16* __restrict__ og)
{
  __shared__ float Mb[256];           // mask bias (1 KB — only LDS use)
  const int flag = *flagp;
  const int t = threadIdx.x, lane = t & 63, wave = t >> 6;
  const int s_ = blockIdx.x, h = blockIdx.y;
  const int g = lane >> 4, l15 = lane & 15;

  Mb[t] = 1e9f * (ldin(mask, s_ * 256 + t, flag) - 1.0f);
  __syncthreads();

  f32x4 zero = {0.f, 0.f, 0.f, 0.f};
  const u16* Qb = Qw + (s_ * 256) * 256 + h * 32;
  const u16* Kb = Kw + (s_ * 256) * 256 + h * 32;
  const u16* Vb = Vt + ((s_ * 8 + h) * 32) * 256;
  const u16* Gb = Gw + (s_ * 256) * 256 + h * 32;
  const u16* zb0 = z_bf + h * 65536;

  #pragma clang loop unroll(disable)
  for (int qt = 0; qt < 4; ++qt) {
    const int qbase = wave * 64 + qt * 16;      // q within s (0..255)
    union { bf16x8 v; uint2 u2[2]; } aq;
    aq.u2[0] = *(const uint2*)(Qb + (qbase + l15) * 256 + g * 4);
    aq.u2[1] = *(const uint2*)(Qb + (qbase + l15) * 256 + 16 + g * 4);

    float sm = 0.f;
    f32x4 O0 = zero, O1 = zero;
    #pragma unroll
    for (int kc = 0; kc < 8; ++kc) {
      unsigned int pw[4];
      #pragma unroll
      for (int hf = 0; hf < 2; ++hf) {
        const int kt = kc * 2 + hf;
        union { bf16x8 v; uint2 u2[2]; } kf;
        kf.u2[0] = *(const uint2*)(Kb + (kt * 16 + l15) * 256 + g * 4);
        kf.u2[1] = *(const uint2*)(Kb + (kt * 16 + l15) * 256 + 16 + g * 4);
        // St: col l15 = q, row g*4+r = k within kt (verified swapped-QK)
        f32x4 S = __builtin_amdgcn_mfma_f32_16x16x32_bf16(kf.v, aq.v, zero, 0, 0, 0);
        float4 mb = *(const float4*)(Mb + kt * 16 + g * 4);
        uint2 zu = *(const uint2*)(zb0 + (qbase + l15) * 256 + kt * 16 + g * 4);
        const u16* zh = (const u16*)&zu;
        float e0 = __expf(S[0] + mb.x + bf2f(zh[0]));
        float e1 = __expf(S[1] + mb.y + bf2f(zh[1]));
        float e2 = __expf(S[2] + mb.z + bf2f(zh[2]));
        float e3 = __expf(S[3] + mb.w + bf2f(zh[3]));
        sm += (e0 + e1) + (e2 + e3);
        pw[hf * 2]     = pk2(e0, e1);
        pw[hf * 2 + 1] = pk2(e2, e3);
      }
      union { bf16x8 v; unsigned int w[4]; } pf;
      pf.w[0] = pw[0]; pf.w[1] = pw[1]; pf.w[2] = pw[2]; pf.w[3] = pw[3];
      union { bf16x8 v; uint2 u2[2]; } vf0, vf1;
      vf0.u2[0] = *(const uint2*)(Vb + l15 * 256        + kc * 32 + g * 4);
      vf0.u2[1] = *(const uint2*)(Vb + l15 * 256        + kc * 32 + 16 + g * 4);
      vf1.u2[0] = *(const uint2*)(Vb + (16 + l15) * 256 + kc * 32 + g * 4);
      vf1.u2[1] = *(const uint2*)(Vb + (16 + l15) * 256 + kc * 32 + 16 + g * 4);
      O0 = __builtin_amdgcn_mfma_f32_16x16x32_bf16(pf.v, vf0.v, O0, 0, 0, 0);
      O1 = __builtin_amdgcn_mfma_f32_16x16x32_bf16(pf.v, vf1.v, O1, 0, 0, 0);
    }
    sm += __shfl_xor(sm, 16, 64);
    sm += __shfl_xor(sm, 32, 64);
    #pragma unroll
    for (int r = 0; r < 4; ++r) {
      float smr = __shfl(sm, g * 4 + r, 64);
      float inv = 1.0f / smr;
      int qq = qbase + g * 4 + r;
      float g0 = bf2f(Gb[qq * 256 + l15]);
      float g1 = bf2f(Gb[qq * 256 + 16 + l15]);
      int base = (s_ * 256 + qq) * 256 + h * 32;
      og[base + l15]      = f2bf(O0[r] * inv * g0);
      og[base + 16 + l15] = f2bf(O1[r] * inv * g1);
    }
  }
}

// ---------------------------------------------------------------------------
// Kernel 5: output projection GEMM (unchanged).  64-row tiles, grid (512,2),
// launch_bounds(256,4) -> 4 blocks/CU.  M=32768, N=256, K=256. +bo.
// ---------------------------------------------------------------------------
__global__ __launch_bounds__(256, 4) void k_outproj(
    const u16* __restrict__ og, const u16* __restrict__ wot,
    const void* __restrict__ bo, const int* __restrict__ flagp,
    void* __restrict__ outv)
{
  const int flag = *flagp;
  const int t = threadIdx.x, lane = t & 63, wave = t >> 6;
  const int wm = (wave >> 1) * 32, wn = (wave & 1) * 64;
  const int rowBase = blockIdx.x * 64;
  const int ct = blockIdx.y;
  const int g = lane >> 4, l15 = lane & 15;

  bf16x8 af[8][2];
  #pragma unroll
  for (int kb = 0; kb < 8; ++kb)
    #pragma unroll
    for (int mt = 0; mt < 2; ++mt)
      af[kb][mt] = *(const bf16x8*)(
          og + (rowBase + wm + mt * 16 + l15) * 256 + kb * 32 + g * 8);

  const u16* Wb = wot + (ct * 128 + wn) * 256;
  f32x4 acc[2][4];
  f32x4 zero = {0.f, 0.f, 0.f, 0.f};
  #pragma unroll
  for (int i = 0; i < 2; ++i)
    #pragma unroll
    for (int j = 0; j < 4; ++j) acc[i][j] = zero;
  #pragma unroll
  for (int kb = 0; kb < 8; ++kb) {
    bf16x8 bb[4];
    #pragma unroll
    for (int nt = 0; nt < 4; ++nt)
      bb[nt] = *(const bf16x8*)(Wb + (nt * 16 + l15) * 256 + kb * 32 + g * 8);
    #pragma unroll
    for (int mt = 0; mt < 2; ++mt)
      #pragma unroll
      for (int nt = 0; nt < 4; ++nt)
        acc[mt][nt] = __builtin_amdgcn_mfma_f32_16x16x32_bf16(
            af[kb][mt], bb[nt], acc[mt][nt], 0, 0, 0);
  }
  #pragma unroll
  for (int mt = 0; mt < 2; ++mt)
    #pragma unroll
    for (int nt = 0; nt < 4; ++nt)
      #pragma unroll
      for (int r = 0; r < 4; ++r) {
        int row = rowBase + wm + mt * 16 + g * 4 + r;
        int col = ct * 128 + wn + nt * 16 + l15;
        float val = acc[mt][nt][r] + ldin(bo, col, flag);
        if (flag) ((float*)outv)[row * 256 + col] = val;
        else      ((u16*)outv)[row * 256 + col]   = f2bf(val);
      }
}

// ---------------------------------------------------------------------------
extern "C" void kernel_launch(void* const* d_in, const int* in_sizes, int n_in,
                              void* d_out, int out_size, void* d_ws, size_t ws_size,
                              hipStream_t stream)
{
  const void* msa  = d_in[0];
  const void* pair = d_in[1];
  const void* mask = d_in[2];
  const void* qng  = d_in[3];
  const void* qnb  = d_in[4];
  const void* png  = d_in[5];
  const void* pnb  = d_in[6];
  const void* w2d  = d_in[7];
  const void* wq   = d_in[8];
  const void* wk   = d_in[9];
  const void* wv   = d_in[10];
  const void* wg   = d_in[11];
  const void* bg   = d_in[12];
  const void* wo   = d_in[13];
  const void* bo   = d_in[14];

  char* ws = (char*)d_ws;
  u16* z_bf  = (u16*)(ws + 0);                  //  1,048,576
  u16* Wt    = (u16*)(ws + 1048576);            //    524,288
  u16* wot   = (u16*)(ws + 1572864);            //    131,072
  int* flag  = (int*)(ws + 1703936);            //        256
  u16* m_bf  = (u16*)(ws + 1704192);            // 16,777,216
  u16* og_ws = m_bf;                            // alias: m_bf dead after qkvg
  u16* Q_ws  = (u16*)(ws + 18481408);           // 16,777,216
  u16* K_ws  = (u16*)(ws + 35258624);           // 16,777,216
  u16* Vt_ws = (u16*)(ws + 52035840);           // 16,777,216
  u16* G_ws  = (u16*)(ws + 68813056);           // 16,777,216 -> ends 85,590,272

  hipLaunchKernelGGL(k_prep, dim3(9296), dim3(256), 0, stream,
                     msa, pair, qng, qnb, png, pnb, w2d,
                     wq, wk, wv, wg, wo, Wt, wot, m_bf, z_bf, flag);
  hipLaunchKernelGGL(k_qkvg, dim3(512, 8), dim3(256), 0, stream,
                     m_bf, Wt, bg, flag, Q_ws, K_ws, Vt_ws, G_ws);
  hipLaunchKernelGGL(k_attn, dim3(128, 8), dim3(256), 0, stream,
                     Q_ws, K_ws, Vt_ws, G_ws, z_bf, mask, flag, og_ws);
  hipLaunchKernelGGL(k_outproj, dim3(512, 2), dim3(256), 0, stream,
                     og_ws, wot, bo, flag, d_out);
}